// Round 1
// baseline (149.640 us; speedup 1.0000x reference)
//
#include <hip/hip_runtime.h>

#define NODES 28
#define PPN   320               // points per node
#define MID   13                // (NODES-2)/2
#define NPTS  (NODES * PPN)     // 8960
#define SIGMA 10.0f
#define FLT_BIG 3.4e38f

// Kernel 1: for each node pair (a,b), compute
//   m_x[i][b] = min over t-points of node b of ||x_i - t||^2   (i in node a)
//   m_t[j][a] = min over x-points of node a of ||x_j - t_j||^2 (j in node b)
// One block per (a,b); 320 threads; both tiles staged in LDS; inner loop
// reads are wave-uniform (broadcast, conflict-free).
__global__ __launch_bounds__(PPN)
void pernode_min_kernel(const float* __restrict__ X,
                        const float* __restrict__ T,
                        float* __restrict__ m_x,
                        float* __restrict__ m_t)
{
    __shared__ float sx[PPN * 3];
    __shared__ float st[PPN * 3];

    const int a = blockIdx.x / NODES;
    const int b = blockIdx.x % NODES;
    const int t = threadIdx.x;

    // stage + clip both node tiles (320 pts * 3 floats each)
    for (int k = t; k < PPN * 3; k += PPN) {
        float vx = X[a * PPN * 3 + k];
        float vt = T[b * PPN * 3 + k];
        sx[k] = fminf(fmaxf(vx, -SIGMA), SIGMA);
        st[k] = fminf(fmaxf(vt, -SIGMA), SIGMA);
    }
    __syncthreads();

    // pass 1: thread t = x-point, min over t-points of node b
    {
        const float x0 = sx[t * 3 + 0];
        const float x1 = sx[t * 3 + 1];
        const float x2 = sx[t * 3 + 2];
        float mn = FLT_BIG;
        #pragma unroll 8
        for (int j = 0; j < PPN; ++j) {
            float d0 = x0 - st[j * 3 + 0];
            float d1 = x1 - st[j * 3 + 1];
            float d2 = x2 - st[j * 3 + 2];
            float d  = d0 * d0 + d1 * d1 + d2 * d2;
            mn = fminf(mn, d);
        }
        m_x[(a * PPN + t) * NODES + b] = mn;
    }

    // pass 2: thread t = t-point, min over x-points of node a
    {
        const float y0 = st[t * 3 + 0];
        const float y1 = st[t * 3 + 1];
        const float y2 = st[t * 3 + 2];
        float mn = FLT_BIG;
        #pragma unroll 8
        for (int i = 0; i < PPN; ++i) {
            float d0 = y0 - sx[i * 3 + 0];
            float d1 = y1 - sx[i * 3 + 1];
            float d2 = y2 - sx[i * 3 + 2];
            float d  = d0 * d0 + d1 * d1 + d2 * d2;
            mn = fminf(mn, d);
        }
        m_t[(b * PPN + t) * NODES + a] = mn;
    }
}

__inline__ __device__ float wave_reduce_sum(float v) {
    #pragma unroll
    for (int off = 32; off > 0; off >>= 1)
        v += __shfl_down(v, off, 64);
    return v;
}

// Kernel 2: per point, fold the 28 per-node minima into the 26-subset sum
// (closed form via min1/argmin/min2) + half-arch term; reduce to scalar.
__global__ __launch_bounds__(256)
void combine_kernel(const float* __restrict__ m,   // [2*NPTS][NODES]
                    float* __restrict__ out)
{
    const int p = blockIdx.x * blockDim.x + threadIdx.x;  // 0 .. 2*NPTS-1
    float tot = 0.0f;
    if (p < 2 * NPTS) {
        const float* row = m + p * NODES;
        const int a = (p % NPTS) / PPN;   // node of this point

        float r[NODES];
        #pragma unroll
        for (int c = 0; c < NODES; ++c) r[c] = row[c];

        // min1 / argmin
        float min1 = FLT_BIG; int c1 = -1;
        #pragma unroll
        for (int c = 0; c < NODES; ++c) {
            if (r[c] < min1) { min1 = r[c]; c1 = c; }
        }
        // min over c != c1
        float min2 = FLT_BIG;
        #pragma unroll
        for (int c = 0; c < NODES; ++c) {
            float v = (c == c1) ? FLT_BIG : r[c];
            min2 = fminf(min2, v);
        }
        // half-arch min
        float H = FLT_BIG;
        if (a < MID) {
            #pragma unroll
            for (int c = 0; c < MID; ++c) H = fminf(H, r[c]);
        } else {
            #pragma unroll
            for (int c = MID; c < NODES; ++c) H = fminf(H, r[c]);
        }

        const int n = (a < NODES - 2) ? (NODES - 3) : (NODES - 2); // 25 or 26
        float S = (float)n * min1;
        if (c1 <= NODES - 3 && c1 != a) S -= (min1 - min2);
        if (a < NODES - 2) {
            const int dup = (a < MID) ? (a + MID) : (a - MID);
            S += (c1 == dup) ? min2 : min1;
        }
        tot = S + H;
    }

    // block reduction -> one atomic per block
    __shared__ float warp_sums[4];
    float ws = wave_reduce_sum(tot);
    const int lane = threadIdx.x & 63;
    const int wid  = threadIdx.x >> 6;
    if (lane == 0) warp_sums[wid] = ws;
    __syncthreads();
    if (wid == 0) {
        float v = (lane < 4) ? warp_sums[lane] : 0.0f;
        v = wave_reduce_sum(v);
        if (lane == 0) atomicAdd(out, v);
    }
}

extern "C" void kernel_launch(void* const* d_in, const int* in_sizes, int n_in,
                              void* d_out, int out_size, void* d_ws, size_t ws_size,
                              hipStream_t stream) {
    const float* X = (const float*)d_in[0];
    const float* T = (const float*)d_in[1];
    float* out = (float*)d_out;

    float* m_x = (float*)d_ws;              // [NPTS][NODES]
    float* m_t = m_x + NPTS * NODES;        // [NPTS][NODES]

    hipMemsetAsync(out, 0, sizeof(float), stream);

    pernode_min_kernel<<<NODES * NODES, PPN, 0, stream>>>(X, T, m_x, m_t);

    const int total = 2 * NPTS;             // 17920
    combine_kernel<<<(total + 255) / 256, 256, 0, stream>>>(m_x, out);
}

// Round 2
// 78.515 us; speedup vs baseline: 1.9059x; 1.9059x over previous
//
#include <hip/hip_runtime.h>

#define NODES  28
#define PPN    320              // points per node
#define MID    13               // (NODES-2)/2
#define NPTS   (NODES * PPN)    // 8960
#define TOTPTS (2 * NPTS)       // 17920
#define SIGMA  10.0f
#define FLT_BIG 3.4e38f

// ---------------------------------------------------------------------------
// Kernel 0 (prep): clip inputs, build float4 tiles.
//   src4 = ( x, y, z, |x|^2 )          for the "query" role
//   tgt4 = (-2x,-2y,-2z, |x|^2 )       for the "database" role
// so dist^2 = dot(tgt4.xyz, src.xyz) + tgt4.w + src4.w  (add src4.w after min)
// Also zeroes d_out (combine atomicAdds into it later in stream order).
// ---------------------------------------------------------------------------
__global__ __launch_bounds__(256)
void prep_kernel(const float* __restrict__ X, const float* __restrict__ T,
                 float4* __restrict__ srcX, float4* __restrict__ tgtX,
                 float4* __restrict__ srcT, float4* __restrict__ tgtT,
                 float* __restrict__ out)
{
    const int i = blockIdx.x * 256 + threadIdx.x;
    if (i == 0) out[0] = 0.0f;
    if (i >= NPTS) return;

    float x0 = fminf(fmaxf(X[3*i+0], -SIGMA), SIGMA);
    float x1 = fminf(fmaxf(X[3*i+1], -SIGMA), SIGMA);
    float x2 = fminf(fmaxf(X[3*i+2], -SIGMA), SIGMA);
    float nx = x0*x0 + x1*x1 + x2*x2;
    srcX[i] = make_float4(x0, x1, x2, nx);
    tgtX[i] = make_float4(-2.f*x0, -2.f*x1, -2.f*x2, nx);

    float t0 = fminf(fmaxf(T[3*i+0], -SIGMA), SIGMA);
    float t1 = fminf(fmaxf(T[3*i+1], -SIGMA), SIGMA);
    float t2 = fminf(fmaxf(T[3*i+2], -SIGMA), SIGMA);
    float nt = t0*t0 + t1*t1 + t2*t2;
    srcT[i] = make_float4(t0, t1, t2, nt);
    tgtT[i] = make_float4(-2.f*t0, -2.f*t1, -2.f*t2, nt);
}

// ---------------------------------------------------------------------------
// Kernel 1: per (source-group, target-node) block, broadcast target tile from
// LDS (one ds_read_b128 per target point), 2 source points per thread.
// Output transposed: m[c][q], c = target node, q = global point id
// (q < NPTS: X-points -> min over T-node c; q >= NPTS: T-points -> min over
// X-node c). Stores are lane-coalesced.
// ---------------------------------------------------------------------------
__global__ __launch_bounds__(PPN)
void pair_min_kernel(const float4* __restrict__ srcX, const float4* __restrict__ tgtX,
                     const float4* __restrict__ srcT, const float4* __restrict__ tgtT,
                     float* __restrict__ m)   // [NODES][TOTPTS]
{
    __shared__ float4 st[PPN];

    const int bid = blockIdx.x;          // 0..783
    const int p   = bid / 392;           // 0: X queries vs T db; 1: T vs X
    const int r   = bid % 392;
    const int g   = r / NODES;           // source pair-group 0..13 (640 pts)
    const int b   = r % NODES;           // target node

    const float4* __restrict__ src = p ? srcT : srcX;
    const float4* __restrict__ tgt = p ? tgtX : tgtT;

    const int t = threadIdx.x;
    st[t] = tgt[b * PPN + t];
    __syncthreads();

    const int i0 = g * 640 + t;
    const int i1 = i0 + PPN;
    const float4 s0 = src[i0];
    const float4 s1 = src[i1];

    float mn0 = FLT_BIG, mn1 = FLT_BIG;
    #pragma unroll 8
    for (int j = 0; j < PPN; ++j) {
        const float4 tp = st[j];
        float d0 = fmaf(tp.x, s0.x, fmaf(tp.y, s0.y, fmaf(tp.z, s0.z, tp.w)));
        float d1 = fmaf(tp.x, s1.x, fmaf(tp.y, s1.y, fmaf(tp.z, s1.z, tp.w)));
        mn0 = fminf(mn0, d0);
        mn1 = fminf(mn1, d1);
    }

    const int q0 = p * NPTS + i0;        // global point id
    float* row = m + (size_t)b * TOTPTS;
    row[q0]        = mn0 + s0.w;
    row[q0 + PPN]  = mn1 + s1.w;
}

__inline__ __device__ float wave_reduce_sum(float v) {
    #pragma unroll
    for (int off = 32; off > 0; off >>= 1)
        v += __shfl_down(v, off, 64);
    return v;
}

// ---------------------------------------------------------------------------
// Kernel 2: fold the 28 per-node minima into the 26-subset closed form +
// half-arch term; reduce to scalar. Reads m[c][q]: for fixed c, lanes read
// consecutive q -> coalesced.
// ---------------------------------------------------------------------------
__global__ __launch_bounds__(256)
void combine_kernel(const float* __restrict__ m,   // [NODES][TOTPTS]
                    float* __restrict__ out)
{
    const int q = blockIdx.x * blockDim.x + threadIdx.x;  // 0 .. TOTPTS-1
    float tot = 0.0f;
    if (q < TOTPTS) {
        const int a = (q % NPTS) / PPN;   // node of this point

        float r[NODES];
        #pragma unroll
        for (int c = 0; c < NODES; ++c) r[c] = m[(size_t)c * TOTPTS + q];

        // min1 / argmin
        float min1 = FLT_BIG; int c1 = -1;
        #pragma unroll
        for (int c = 0; c < NODES; ++c) {
            if (r[c] < min1) { min1 = r[c]; c1 = c; }
        }
        // min over c != c1
        float min2 = FLT_BIG;
        #pragma unroll
        for (int c = 0; c < NODES; ++c) {
            float v = (c == c1) ? FLT_BIG : r[c];
            min2 = fminf(min2, v);
        }
        // half-arch min
        float H = FLT_BIG;
        if (a < MID) {
            #pragma unroll
            for (int c = 0; c < MID; ++c) H = fminf(H, r[c]);
        } else {
            #pragma unroll
            for (int c = MID; c < NODES; ++c) H = fminf(H, r[c]);
        }

        const int n = (a < NODES - 2) ? (NODES - 3) : (NODES - 2); // 25 or 26
        float S = (float)n * min1;
        if (c1 <= NODES - 3 && c1 != a) S -= (min1 - min2);
        if (a < NODES - 2) {
            const int dup = (a < MID) ? (a + MID) : (a - MID);
            S += (c1 == dup) ? min2 : min1;
        }
        tot = S + H;
    }

    __shared__ float warp_sums[4];
    float ws = wave_reduce_sum(tot);
    const int lane = threadIdx.x & 63;
    const int wid  = threadIdx.x >> 6;
    if (lane == 0) warp_sums[wid] = ws;
    __syncthreads();
    if (wid == 0) {
        float v = (lane < 4) ? warp_sums[lane] : 0.0f;
        v = wave_reduce_sum(v);
        if (lane == 0) atomicAdd(out, v);
    }
}

extern "C" void kernel_launch(void* const* d_in, const int* in_sizes, int n_in,
                              void* d_out, int out_size, void* d_ws, size_t ws_size,
                              hipStream_t stream) {
    const float* X = (const float*)d_in[0];
    const float* T = (const float*)d_in[1];
    float* out = (float*)d_out;

    // workspace layout
    float* m = (float*)d_ws;                         // [NODES][TOTPTS] = 2.0 MB
    float4* srcX = (float4*)(m + (size_t)NODES * TOTPTS);
    float4* tgtX = srcX + NPTS;
    float4* srcT = tgtX + NPTS;
    float4* tgtT = srcT + NPTS;                      // +573 KB

    prep_kernel<<<(NPTS + 255) / 256, 256, 0, stream>>>(X, T, srcX, tgtX, srcT, tgtT, out);
    pair_min_kernel<<<784, PPN, 0, stream>>>(srcX, tgtX, srcT, tgtT, m);
    combine_kernel<<<(TOTPTS + 255) / 256, 256, 0, stream>>>(m, out);
}

// Round 3
// 75.115 us; speedup vs baseline: 1.9921x; 1.0453x over previous
//
#include <hip/hip_runtime.h>

#define NODES  28
#define PPN    320              // points per node
#define MID    13               // (NODES-2)/2
#define NPTS   (NODES * PPN)    // 8960
#define TOTPTS (2 * NPTS)       // 17920
#define SIGMA  10.0f
#define FLT_BIG 3.4e38f

#define BT    128               // threads per pair block (2 waves)
#define RPT   2                 // source points per thread
#define GPTS  (BT * RPT)        // 256 source points per block
#define NGRP  (NPTS / GPTS)     // 35 source groups per direction

// ---------------------------------------------------------------------------
// Phase 1 (fused prep + pairwise min): one block per
// (direction p, source-group g, db-node b). Block clips+packs db node b's
// 320 points into LDS as (-2x,-2y,-2z,|x|^2); each thread owns 2 clipped
// source points (x,y,z,|x|^2 in regs). dist^2 = dot(db.xyz, s.xyz) + db.w
// (+ s.w added once after the min). Inner loop: 2 db points per step so the
// two fmins fuse to v_min3_f32 -> 3.5 VALU/distance. Output m[b][q] is
// lane-coalesced.
// ---------------------------------------------------------------------------
__global__ __launch_bounds__(BT)
void pair_min_kernel(const float* __restrict__ X, const float* __restrict__ T,
                     float* __restrict__ m)   // [NODES][TOTPTS]
{
    __shared__ float4 st[PPN];

    const int bid = blockIdx.x;              // 0 .. 2*NGRP*NODES-1
    const int p   = bid / (NGRP * NODES);    // 0: X queries vs T db; 1: T vs X
    const int r   = bid % (NGRP * NODES);
    const int g   = r / NODES;               // source group (256 pts)
    const int b   = r % NODES;               // db node

    const float* __restrict__ src = p ? T : X;
    const float* __restrict__ db  = p ? X : T;

    const int t = threadIdx.x;

    // stage + clip + pack db node b (320 pts, 15 scalar loads/thread)
    for (int j = t; j < PPN; j += BT) {
        const float* q = db + (size_t)(b * PPN + j) * 3;
        float v0 = fminf(fmaxf(q[0], -SIGMA), SIGMA);
        float v1 = fminf(fmaxf(q[1], -SIGMA), SIGMA);
        float v2 = fminf(fmaxf(q[2], -SIGMA), SIGMA);
        float n  = v0*v0 + v1*v1 + v2*v2;
        st[j] = make_float4(-2.f*v0, -2.f*v1, -2.f*v2, n);
    }

    // own source points (clip + norm)
    const int i0 = g * GPTS + t;
    const int i1 = i0 + BT;
    float4 s0, s1;
    {
        const float* q0 = src + (size_t)i0 * 3;
        float a0 = fminf(fmaxf(q0[0], -SIGMA), SIGMA);
        float a1 = fminf(fmaxf(q0[1], -SIGMA), SIGMA);
        float a2 = fminf(fmaxf(q0[2], -SIGMA), SIGMA);
        s0 = make_float4(a0, a1, a2, a0*a0 + a1*a1 + a2*a2);
        const float* q1 = src + (size_t)i1 * 3;
        float b0 = fminf(fmaxf(q1[0], -SIGMA), SIGMA);
        float b1 = fminf(fmaxf(q1[1], -SIGMA), SIGMA);
        float b2 = fminf(fmaxf(q1[2], -SIGMA), SIGMA);
        s1 = make_float4(b0, b1, b2, b0*b0 + b1*b1 + b2*b2);
    }
    __syncthreads();

    float mn0 = FLT_BIG, mn1 = FLT_BIG;
    #pragma unroll 4
    for (int j = 0; j < PPN; j += 2) {
        const float4 ta = st[j];
        const float4 tb = st[j + 1];
        float d0a = fmaf(ta.x, s0.x, fmaf(ta.y, s0.y, fmaf(ta.z, s0.z, ta.w)));
        float d0b = fmaf(tb.x, s0.x, fmaf(tb.y, s0.y, fmaf(tb.z, s0.z, tb.w)));
        float d1a = fmaf(ta.x, s1.x, fmaf(ta.y, s1.y, fmaf(ta.z, s1.z, ta.w)));
        float d1b = fmaf(tb.x, s1.x, fmaf(tb.y, s1.y, fmaf(tb.z, s1.z, tb.w)));
        mn0 = fminf(mn0, fminf(d0a, d0b));   // -> v_min3_f32
        mn1 = fminf(mn1, fminf(d1a, d1b));
    }

    const int q0 = p * NPTS + i0;            // global point id
    float* row = m + (size_t)b * TOTPTS;
    row[q0]      = mn0 + s0.w;
    row[q0 + BT] = mn1 + s1.w;
}

__inline__ __device__ float wave_reduce_sum(float v) {
    #pragma unroll
    for (int off = 32; off > 0; off >>= 1)
        v += __shfl_down(v, off, 64);
    return v;
}

// ---------------------------------------------------------------------------
// Phase 2: fold the 28 per-node minima into the 26-subset closed form +
// half-arch term; reduce to scalar. m[c][q]: for fixed c, lanes read
// consecutive q -> coalesced.
// ---------------------------------------------------------------------------
__global__ __launch_bounds__(256)
void combine_kernel(const float* __restrict__ m,   // [NODES][TOTPTS]
                    float* __restrict__ out)
{
    const int q = blockIdx.x * blockDim.x + threadIdx.x;  // 0 .. TOTPTS-1
    float tot = 0.0f;
    if (q < TOTPTS) {
        const int a = (q % NPTS) / PPN;   // node of this point

        float r[NODES];
        #pragma unroll
        for (int c = 0; c < NODES; ++c) r[c] = m[(size_t)c * TOTPTS + q];

        // min1 / argmin
        float min1 = FLT_BIG; int c1 = -1;
        #pragma unroll
        for (int c = 0; c < NODES; ++c) {
            if (r[c] < min1) { min1 = r[c]; c1 = c; }
        }
        // min over c != c1
        float min2 = FLT_BIG;
        #pragma unroll
        for (int c = 0; c < NODES; ++c) {
            float v = (c == c1) ? FLT_BIG : r[c];
            min2 = fminf(min2, v);
        }
        // half-arch min
        float H = FLT_BIG;
        if (a < MID) {
            #pragma unroll
            for (int c = 0; c < MID; ++c) H = fminf(H, r[c]);
        } else {
            #pragma unroll
            for (int c = MID; c < NODES; ++c) H = fminf(H, r[c]);
        }

        const int n = (a < NODES - 2) ? (NODES - 3) : (NODES - 2); // 25 or 26
        float S = (float)n * min1;
        if (c1 <= NODES - 3 && c1 != a) S -= (min1 - min2);
        if (a < NODES - 2) {
            const int dup = (a < MID) ? (a + MID) : (a - MID);
            S += (c1 == dup) ? min2 : min1;
        }
        tot = S + H;
    }

    __shared__ float warp_sums[4];
    float ws = wave_reduce_sum(tot);
    const int lane = threadIdx.x & 63;
    const int wid  = threadIdx.x >> 6;
    if (lane == 0) warp_sums[wid] = ws;
    __syncthreads();
    if (wid == 0) {
        float v = (lane < 4) ? warp_sums[lane] : 0.0f;
        v = wave_reduce_sum(v);
        if (lane == 0) atomicAdd(out, v);
    }
}

extern "C" void kernel_launch(void* const* d_in, const int* in_sizes, int n_in,
                              void* d_out, int out_size, void* d_ws, size_t ws_size,
                              hipStream_t stream) {
    const float* X = (const float*)d_in[0];
    const float* T = (const float*)d_in[1];
    float* out = (float*)d_out;
    float* m   = (float*)d_ws;               // [NODES][TOTPTS] = 2.0 MB

    hipMemsetAsync(out, 0, sizeof(float), stream);
    pair_min_kernel<<<2 * NGRP * NODES, BT, 0, stream>>>(X, T, m);
    combine_kernel<<<(TOTPTS + 255) / 256, 256, 0, stream>>>(m, out);
}